// Round 1
// baseline (1857734.570 us; speedup 1.0000x reference)
//
#include <hip/hip_runtime.h>
#include <math.h>
#include <stdio.h>

// JAX >= 0.4.36 defaults jax_threefry_partitionable=True. If output 0 comes
// back as pure garbage (absmax ~ 32000 everywhere), flip this to 0.
#ifndef JAX_PARTITIONABLE
#define JAX_PARTITIONABLE 1
#endif

namespace {

constexpr int B  = 512;
constexpr int S  = 256;
constexpr int E  = 256;
constexpr int H  = 512;
constexpr int V  = 32000;
constexpr int G3 = 3 * H;      // 1536
constexpr int VBLK = 128;
constexpr int BBLK = 128;
constexpr int NVC  = V / VBLK; // 250

// ---------------- Threefry-2x32, 20 rounds (bit-exact JAX) ----------------
__device__ __forceinline__ void tf2x32(unsigned k0, unsigned k1,
                                       unsigned x0, unsigned x1,
                                       unsigned& o0, unsigned& o1) {
  unsigned ks2 = k0 ^ k1 ^ 0x1BD11BDAu;
  x0 += k0; x1 += k1;
#define TFR(r) { x0 += x1; x1 = (x1 << (r)) | (x1 >> (32 - (r))); x1 ^= x0; }
  TFR(13) TFR(15) TFR(26) TFR(6)   x0 += k1;  x1 += ks2 + 1u;
  TFR(17) TFR(29) TFR(16) TFR(24)  x0 += ks2; x1 += k0 + 2u;
  TFR(13) TFR(15) TFR(26) TFR(6)   x0 += k0;  x1 += k1 + 3u;
  TFR(17) TFR(29) TFR(16) TFR(24)  x0 += k1;  x1 += ks2 + 4u;
  TFR(13) TFR(15) TFR(26) TFR(6)   x0 += ks2; x1 += k0 + 5u;
#undef TFR
  o0 = x0; o1 = x1;
}

__device__ __forceinline__ float u01_from_bits(unsigned bits) {
  // bitcast(0x3f800000 | bits>>9) - 1.0f : exactly JAX's uniform [0,1)
  return __uint_as_float(0x3f800000u | (bits >> 9)) - 1.0f;
}

__device__ __forceinline__ float gumbel_from_bits(unsigned bits) {
  float u = u01_from_bits(bits);
  // uniform(minval=tiny, maxval=1): u*(1-tiny)+tiny == (u==0 ? tiny : u) in f32
  if (u == 0.0f) u = 1.1754943508222875e-38f;
  float w = (float)(-log((double)u));   // correctly-rounded f32 of -log(u)
  return (float)(-log((double)w));      // g = -log(-log(u))
}

// ---------------- init: per-step keys ----------------
__global__ void k_init_rng(unsigned* __restrict__ kq, unsigned* __restrict__ ke) {
  int t = threadIdx.x;  // 256 threads, 1 block
  unsigned h0, h1, e0, e1, g0, g1;
#if JAX_PARTITIONABLE
  tf2x32(0u, 42u, 0u, (unsigned)t, h0, h1);          // keys[t] = block(root, 0, t)
  tf2x32(h0, h1, 0u, 0u, e0, e1);                    // k_eps
  tf2x32(h0, h1, 0u, 1u, g0, g1);                    // k_gum
#else
  // original (non-partitionable) split semantics
  unsigned a0, a1, b0, b1;
  if (t < 128) {
    tf2x32(0u, 42u, (unsigned)(2*t),   (unsigned)(256+2*t), a0, a1);
    tf2x32(0u, 42u, (unsigned)(2*t+1), (unsigned)(257+2*t), b0, b1);
    h0 = a0; h1 = b0;
  } else {
    int j = 2*t - 256;
    tf2x32(0u, 42u, (unsigned)j,     (unsigned)(256+j), a0, a1);
    tf2x32(0u, 42u, (unsigned)(j+1), (unsigned)(257+j), b0, b1);
    h0 = a1; h1 = b1;
  }
  unsigned p0, p1, q0, q1;
  tf2x32(h0, h1, 0u, 2u, p0, p1);
  tf2x32(h0, h1, 1u, 3u, q0, q1);
  e0 = p0; e1 = q0; g0 = p1; g1 = q1;
#endif
  ke[2*t] = e0; ke[2*t+1] = e1;
  kq[2*t] = g0; kq[2*t+1] = g1;
}

// ---------------- init: epsilon-greedy draw mask ----------------
__global__ void k_init_draws(const unsigned* __restrict__ ke,
                             unsigned char* __restrict__ draws) {
  int t = blockIdx.x;      // 0..255
  int b = threadIdx.x;     // 0..511
  unsigned k0 = ke[2*t], k1 = ke[2*t+1];
  unsigned bits, y0, y1;
#if JAX_PARTITIONABLE
  tf2x32(k0, k1, 0u, (unsigned)b, y0, y1);
  bits = y0 ^ y1;
#else
  if (b < 256) { tf2x32(k0, k1, (unsigned)b,       (unsigned)(256+b), y0, y1); bits = y0; }
  else         { tf2x32(k0, k1, (unsigned)(b-256), (unsigned)b,       y0, y1); bits = y1; }
#endif
  float u   = u01_from_bits(bits);
  float tf  = (float)t;
  float ex  = expf(__fmul_rn(-4.0f, tf) / 10000.0f);
  float eps = __fadd_rn(0.05f, __fmul_rn(0.95f, ex));  // separate roundings like ref
  draws[t*B + b] = (eps >= u) ? 1 : 0;
}

// ---------------- init: h=0, x = embedding[0] ----------------
__global__ void k_init_state(const float* __restrict__ emb,
                             float* __restrict__ x, float* __restrict__ h) {
  int b = blockIdx.x, tid = threadIdx.x;  // 256 threads
  x[b*E + tid] = emb[tid];
  h[b*H + tid] = 0.0f;
  h[b*H + 256 + tid] = 0.0f;
}

// ---------------- GRU gate GEMMs: gi = x@w_ih^T + b_ih ; gh = h@w_hh^T + b_hh ----------------
__global__ __launch_bounds__(256) void k_gates(
    const float* __restrict__ x, const float* __restrict__ h,
    const float* __restrict__ w_ih, const float* __restrict__ w_hh,
    const float* __restrict__ b_ih, const float* __restrict__ b_hh,
    float* __restrict__ gi, float* __restrict__ gh) {
  const int z = blockIdx.z;
  const float* A    = z ? h    : x;
  const float* W    = z ? w_hh : w_ih;
  const float* bias = z ? b_hh : b_ih;
  float*       C    = z ? gh   : gi;
  const int K       = z ? H    : E;

  __shared__ float As[16][65];
  __shared__ float Ws[16][65];
  const int tid = threadIdx.x;
  const int tx = tid & 15, ty = tid >> 4;
  const int row0 = blockIdx.y * 64, col0 = blockIdx.x * 64;
  float acc[4][4] = {};
  for (int k0 = 0; k0 < K; k0 += 16) {
#pragma unroll
    for (int l = 0; l < 4; l++) {
      int idx = tid + l*256;
      int r = idx >> 4, kk = idx & 15;
      As[kk][r] = A[(row0 + r)*K + k0 + kk];
      Ws[kk][r] = W[(col0 + r)*K + k0 + kk];
    }
    __syncthreads();
#pragma unroll
    for (int kk = 0; kk < 16; kk++) {
      float a[4], w[4];
#pragma unroll
      for (int i = 0; i < 4; i++) a[i] = As[kk][ty*4+i];
#pragma unroll
      for (int j = 0; j < 4; j++) w[j] = Ws[kk][tx*4+j];
#pragma unroll
      for (int i = 0; i < 4; i++)
#pragma unroll
        for (int j = 0; j < 4; j++) acc[i][j] = fmaf(a[i], w[j], acc[i][j]);
    }
    __syncthreads();
  }
#pragma unroll
  for (int i = 0; i < 4; i++) {
    int r = row0 + ty*4 + i;
#pragma unroll
    for (int j = 0; j < 4; j++) {
      int c = col0 + tx*4 + j;
      C[r*G3 + c] = __fadd_rn(acc[i][j], bias[c]);
    }
  }
}

// ---------------- GRU elementwise update (replicates ref rounding order) ----------------
__device__ __forceinline__ float sigm_acc(float v) {
  return (float)(1.0 / (1.0 + exp(-(double)v)));
}
__device__ __forceinline__ float tanh_acc(float v) {
  return (float)tanh((double)v);
}

__global__ void k_gru_update(const float* __restrict__ gi,
                             const float* __restrict__ gh,
                             float* __restrict__ h) {
  int idx = blockIdx.x*256 + threadIdx.x;   // B*H
  int b = idx >> 9, j = idx & 511;
  const float* gib = gi + b*G3;
  const float* ghb = gh + b*G3;
  float r  = sigm_acc(__fadd_rn(gib[j],     ghb[j]));
  float zz = sigm_acc(__fadd_rn(gib[H+j],   ghb[H+j]));
  float nn = tanh_acc(__fadd_rn(gib[2*H+j], __fmul_rn(r, ghb[2*H+j])));
  float hv = h[b*H + j];
  // (1-z)*n + z*h with separate roundings
  float t1 = __fmul_rn(__fsub_rn(1.0f, zz), nn);
  float t2 = __fmul_rn(zz, hv);
  h[b*H + j] = __fadd_rn(t1, t2);
}

// ---------------- fused logits GEMM + gumbel/argmax/online-softmax partials ----------------
__global__ __launch_bounds__(256) void k_logits(
    const float* __restrict__ h, const float* __restrict__ w_out,
    const float* __restrict__ b_out,
    const unsigned* __restrict__ kq, const unsigned char* __restrict__ draws,
    float* __restrict__ pmax, float* __restrict__ psum,
    float* __restrict__ pval, int* __restrict__ pvv, float* __restrict__ plog,
    int t) {
  const int vblk = blockIdx.x;        // 0..249
  const int bblk = blockIdx.y;        // 0..3
  const int tid  = threadIdx.x;
  const int tx = tid & 15, ty = tid >> 4;
  const int v0 = vblk * VBLK, b0 = bblk * BBLK;

  __shared__ float As[16][BBLK + 4];
  __shared__ float Ws[16][VBLK + 4];
  float acc[8][8] = {};

  for (int k0 = 0; k0 < H; k0 += 16) {
#pragma unroll
    for (int l = 0; l < 8; l++) {
      int idx = tid + l*256;
      int r = idx >> 4, kk = idx & 15;
      As[kk][r] = h[(b0 + r)*H + k0 + kk];
      Ws[kk][r] = w_out[(v0 + r)*H + k0 + kk];
    }
    __syncthreads();
#pragma unroll
    for (int kk = 0; kk < 16; kk++) {
      float a[8], w[8];
#pragma unroll
      for (int i = 0; i < 8; i++) a[i] = As[kk][ty*8+i];
#pragma unroll
      for (int j = 0; j < 8; j++) w[j] = Ws[kk][tx*8+j];
#pragma unroll
      for (int i = 0; i < 8; i++)
#pragma unroll
        for (int j = 0; j < 8; j++) acc[i][j] = fmaf(a[i], w[j], acc[i][j]);
    }
    __syncthreads();
  }

  const unsigned g0 = kq[2*t], g1 = kq[2*t+1];
#pragma unroll 1
  for (int i = 0; i < 8; i++) {
    const int b = b0 + ty*8 + i;
    const bool drawn = draws[t*B + b] != 0;
    // add bias (separate add, like ref), local max over this thread's 8 cols
    float lmax = -INFINITY;
#pragma unroll
    for (int j = 0; j < 8; j++) {
      acc[i][j] = __fadd_rn(acc[i][j], b_out[v0 + tx*8 + j]);
      lmax = fmaxf(lmax, acc[i][j]);
    }
    // reduce max across the 16-lane tx group
#pragma unroll
    for (int m = 1; m < 16; m <<= 1) lmax = fmaxf(lmax, __shfl_xor(lmax, m, 64));

    float lsum = 0.0f;
    float bval = -INFINITY; int bv = 0; float blog = 0.0f;
#pragma unroll
    for (int j = 0; j < 8; j++) {
      const int v = v0 + tx*8 + j;
      lsum += expf(acc[i][j] - lmax);
      unsigned bits, y0, y1;
#if JAX_PARTITIONABLE
      tf2x32(g0, g1, 0u, (unsigned)(b*V + v), y0, y1);
      bits = y0 ^ y1;
#else
      {
        const unsigned N2 = (unsigned)(B/2) * (unsigned)V;
        unsigned ii = (unsigned)(b*V + v);
        unsigned jj = (b < 256) ? ii : ii - N2;
        tf2x32(g0, g1, jj, N2 + jj, y0, y1);
        bits = (b < 256) ? y0 : y1;
      }
#endif
      float key;
      if (drawn) {
        // epsilon row: argmax(const + g) == argmax(raw mantissa bits) — EXACT
        key = (float)(bits >> 9);            // < 2^23, exact in f32
      } else {
        key = __fadd_rn(acc[i][j], gumbel_from_bits(bits));  // logits + g
      }
      if (key > bval || (key == bval && v < bv)) { bval = key; bv = v; blog = acc[i][j]; }
    }
    // cross-lane reduce: sum + lexicographic (val, -v) max
#pragma unroll
    for (int m = 1; m < 16; m <<= 1) {
      lsum += __shfl_xor(lsum, m, 64);
      float oval = __shfl_xor(bval, m, 64);
      int   ov   = __shfl_xor(bv,   m, 64);
      float olog = __shfl_xor(blog, m, 64);
      if (oval > bval || (oval == bval && ov < bv)) { bval = oval; bv = ov; blog = olog; }
    }
    if (tx == 0) {
      int p = b * NVC + vblk;
      pmax[p] = lmax; psum[p] = lsum; pval[p] = bval; pvv[p] = bv; plog[p] = blog;
    }
  }
}

// ---------------- per-row combine: lse, sample, lp, x_next gather ----------------
__global__ __launch_bounds__(256) void k_sample(
    const float* __restrict__ pmax, const float* __restrict__ psum,
    const float* __restrict__ pval, const int* __restrict__ pvv,
    const float* __restrict__ plog,
    const float* __restrict__ emb, float* __restrict__ x,
    float* __restrict__ out_samples, float* __restrict__ out_lps, int t) {
  const int b = blockIdx.x;
  const int tid = threadIdx.x;
  __shared__ float sA[256], sV[256], sL[256];
  __shared__ int   sI[256];

  float m = -INFINITY;
  for (int c = tid; c < NVC; c += 256) m = fmaxf(m, pmax[b*NVC + c]);
  sA[tid] = m; __syncthreads();
  for (int s = 128; s > 0; s >>= 1) {
    if (tid < s) sA[tid] = fmaxf(sA[tid], sA[tid+s]);
    __syncthreads();
  }
  const float M = sA[0];
  __syncthreads();

  float sum = 0.0f; float bval = -INFINITY; int bv = 0; float blog = 0.0f;
  for (int c = tid; c < NVC; c += 256) {
    int p = b*NVC + c;
    sum += psum[p] * expf(pmax[p] - M);
    float v = pval[p]; int vi = pvv[p];
    if (v > bval || (v == bval && vi < bv)) { bval = v; bv = vi; blog = plog[p]; }
  }
  sA[tid] = sum; sV[tid] = bval; sI[tid] = bv; sL[tid] = blog;
  __syncthreads();
  for (int s = 128; s > 0; s >>= 1) {
    if (tid < s) {
      sA[tid] += sA[tid+s];
      if (sV[tid+s] > sV[tid] || (sV[tid+s] == sV[tid] && sI[tid+s] < sI[tid])) {
        sV[tid] = sV[tid+s]; sI[tid] = sI[tid+s]; sL[tid] = sL[tid+s];
      }
    }
    __syncthreads();
  }
  const int sampled = sI[0];
  if (tid == 0) {
    float lse = (float)log((double)sA[0]);
    float lp  = __fsub_rn(__fsub_rn(sL[0], M), lse);  // (logit - max) - log(sum)
    out_samples[b*S + t] = (float)sampled;
    out_lps[b*S + t]     = lp;
  }
  // x_next = embedding[sampled]
  x[b*E + tid] = emb[sampled*E + tid];
}

} // namespace

extern "C" void kernel_launch(void* const* d_in, const int* in_sizes, int n_in,
                              void* d_out, int out_size, void* d_ws, size_t ws_size,
                              hipStream_t stream) {
  (void)in_sizes; (void)n_in; (void)out_size;
  const float* emb   = (const float*)d_in[0];
  const float* w_ih  = (const float*)d_in[1];
  const float* w_hh  = (const float*)d_in[2];
  const float* b_ih  = (const float*)d_in[3];
  const float* b_hh  = (const float*)d_in[4];
  const float* w_out = (const float*)d_in[5];
  const float* b_out = (const float*)d_in[6];
  float* out = (float*)d_out;

  char* wsb = (char*)d_ws;
  size_t off = 0;
  auto alloc = [&](size_t nbytes) {
    char* p = wsb + off;
    off += (nbytes + 255) & ~size_t(255);
    return p;
  };
  float* h    = (float*)alloc((size_t)B*H*4);
  float* x    = (float*)alloc((size_t)B*E*4);
  float* gi   = (float*)alloc((size_t)B*G3*4);
  float* gh   = (float*)alloc((size_t)B*G3*4);
  float* pmax = (float*)alloc((size_t)B*NVC*4);
  float* psum = (float*)alloc((size_t)B*NVC*4);
  float* pval = (float*)alloc((size_t)B*NVC*4);
  float* plog = (float*)alloc((size_t)B*NVC*4);
  int*   pvv  = (int*)alloc((size_t)B*NVC*4);
  unsigned* kq = (unsigned*)alloc((size_t)S*2*4);
  unsigned* ke = (unsigned*)alloc((size_t)S*2*4);
  unsigned char* draws = (unsigned char*)alloc((size_t)S*B);
  if (off > ws_size) {
    fprintf(stderr, "kernel_launch: workspace too small (need %zu, have %zu)\n",
            off, ws_size);
    return;
  }

  k_init_rng<<<1, S, 0, stream>>>(kq, ke);
  k_init_draws<<<S, B, 0, stream>>>(ke, draws);
  k_init_state<<<B, 256, 0, stream>>>(emb, x, h);

  for (int t = 0; t < S; t++) {
    k_gates<<<dim3(G3/64, B/64, 2), 256, 0, stream>>>(x, h, w_ih, w_hh,
                                                      b_ih, b_hh, gi, gh);
    k_gru_update<<<(B*H)/256, 256, 0, stream>>>(gi, gh, h);
    k_logits<<<dim3(NVC, B/BBLK), 256, 0, stream>>>(h, w_out, b_out, kq, draws,
                                                    pmax, psum, pval, pvv, plog, t);
    k_sample<<<B, 256, 0, stream>>>(pmax, psum, pval, pvv, plog, emb, x,
                                    out, out + (size_t)B*S, t);
  }
}